// Round 10
// baseline (120.604 us; speedup 1.0000x reference)
//
#include <hip/hip_runtime.h>

typedef __fp16 half2_t __attribute__((ext_vector_type(2)));

static constexpr int IMG = 512;

__device__ __forceinline__ float gd_acc(float d, float acc) {
    const float t    = fmaf(d, d, 1.0f);
    const float rinv = __builtin_amdgcn_rcpf(t);
    const float e    = __builtin_amdgcn_exp2f(
                           -1.442695040888963f * __builtin_fabsf(d) * rinv);
    return fmaf(e, d, acc);
}

// Packed-weight layout in ws (floats): per step t, per ch k: base = t*64 + k*8
//   [0..3] = half2 pairs (w0w1, w2w3, w4w5, w6w7) bit-cast into float
//   [4] = w8 (f32), [5] = bias (f32), [6..7] pad
__global__ void pack_weights(const float* __restrict__ W,
                             const float* __restrict__ b,
                             float* __restrict__ wp)
{
    const int id = threadIdx.x;                  // need 24
    if (id >= 24) return;
    const int t = id / 8, k = id % 8;
    const float* w = W + (t * 8 + k) * 9;
    float* o = wp + t * 64 + k * 8;
    o[0] = __builtin_bit_cast(float, __builtin_amdgcn_cvt_pkrtz(w[0], w[1]));
    o[1] = __builtin_bit_cast(float, __builtin_amdgcn_cvt_pkrtz(w[2], w[3]));
    o[2] = __builtin_bit_cast(float, __builtin_amdgcn_cvt_pkrtz(w[4], w[5]));
    o[3] = __builtin_bit_cast(float, __builtin_amdgcn_cvt_pkrtz(w[6], w[7]));
    o[4] = w[8];
    o[5] = b[t * 8 + k];
}

// One diffusion step, global->global, 4 px/thread, dot2-f16 conv, f32 accumulate.
__global__ __launch_bounds__(256) void ad_step(
    const float* __restrict__ in, float* __restrict__ outp,
    const float* __restrict__ wp)
{
    const int tid = threadIdx.x;
    const int x0  = blockIdx.x * 64 + (tid & 15) * 4;   // 0,4,...,508
    const int y   = blockIdx.y * 16 + (tid >> 4);       // 0..511
    const float* __restrict__ src = in + (size_t)blockIdx.z * (IMG * IMG);

    float L[3][12];
    const bool xfast = (x0 >= 4) && (x0 <= 504);        // cols x0-4..x0+7 in-image
#pragma unroll
    for (int dy = 0; dy < 3; ++dy) {
        const int yy = y + dy - 1;
        const bool rowok = (unsigned)yy < (unsigned)IMG;
        if (xfast && rowok) {
            const float* p = src + yy * IMG + x0 - 4;   // 16B-aligned
            *(float4*)&L[dy][0] = *(const float4*)(p);
            *(float4*)&L[dy][4] = *(const float4*)(p + 4);
            *(float4*)&L[dy][8] = *(const float4*)(p + 8);
        } else {
#pragma unroll
            for (int j = 0; j < 12; ++j) {
                const int col = x0 - 4 + j;
                L[dy][j] = (rowok && (unsigned)col < (unsigned)IMG)
                               ? src[yy * IMG + col] : 0.f;
            }
        }
    }

    // Pack pixel input pairs once, shared by all 8 channels.
    // px i taps: (L0[3+i],L0[4+i]) (L0[5+i],L1[3+i]) (L1[4+i],L1[5+i])
    //            (L2[3+i],L2[4+i]) + single L2[5+i] (f32)
    half2_t PA[4], PB[4], PC[4], PD[4];
#pragma unroll
    for (int i = 0; i < 4; ++i) {
        PA[i] = __builtin_amdgcn_cvt_pkrtz(L[0][3+i], L[0][4+i]);
        PB[i] = __builtin_amdgcn_cvt_pkrtz(L[0][5+i], L[1][3+i]);
        PC[i] = __builtin_amdgcn_cvt_pkrtz(L[1][4+i], L[1][5+i]);
        PD[i] = __builtin_amdgcn_cvt_pkrtz(L[2][3+i], L[2][4+i]);
    }

    float acc[4] = {0.f, 0.f, 0.f, 0.f};
#pragma unroll
    for (int k = 0; k < 8; ++k) {
        const float* wk = wp + k * 8;                    // uniform -> s_load
        const half2_t wA = __builtin_bit_cast(half2_t, wk[0]);
        const half2_t wB = __builtin_bit_cast(half2_t, wk[1]);
        const half2_t wC = __builtin_bit_cast(half2_t, wk[2]);
        const half2_t wD = __builtin_bit_cast(half2_t, wk[3]);
        const float   w8 = wk[4], bk = wk[5];
#pragma unroll
        for (int i = 0; i < 4; ++i) {
            float d = fmaf(w8, L[2][5+i], bk);
            d = __builtin_amdgcn_fdot2(wA, PA[i], d, false);
            d = __builtin_amdgcn_fdot2(wB, PB[i], d, false);
            d = __builtin_amdgcn_fdot2(wC, PC[i], d, false);
            d = __builtin_amdgcn_fdot2(wD, PD[i], d, false);
            acc[i] = gd_acc(d, acc[i]);
        }
    }

    float4 v;
    v.x = L[1][4] - acc[0] * 0.125f;
    v.y = L[1][5] - acc[1] * 0.125f;
    v.z = L[1][6] - acc[2] * 0.125f;
    v.w = L[1][7] - acc[3] * 0.125f;
    *(float4*)&outp[(size_t)blockIdx.z * (IMG * IMG) + y * IMG + x0] = v;
}

// -------- Fallback: fused LDS kernel (only if ws too small) --------
static constexpr int TXF = 64;
static constexpr int TYF = 16;
static constexpr int LST = 72;
static constexpr int SROWS  = TYF + 6;
static constexpr int NSTAGE = SROWS * 18;

template<int WOFF, int NR, int RLO, int NG, bool TO_GLOBAL>
__device__ __forceinline__ void diffuse_step(
    const float* __restrict__ prev, float* __restrict__ cur,
    const float* __restrict__ Wt, const float* __restrict__ bt,
    int xoff, int ty0, int tx0, int tid, float* __restrict__ gout)
{
    constexpr int LOADW  = WOFF ? 8 : 6;
    constexpr int NITEMS = NR * NG;

    for (int idx = tid; idx < NITEMS; idx += 64) {
        const int rr = idx / NG, j = idx - rr * NG;
        const int r  = RLO + rr, c0 = 4 * j;
        const float* base = prev + (r - 1) * LST + c0;

        float L0[LOADW], L1[LOADW], L2[LOADW];
        *(float4*)&L0[0] = *(const float4*)(base);
        *(float4*)&L1[0] = *(const float4*)(base + LST);
        *(float4*)&L2[0] = *(const float4*)(base + 2 * LST);
        if (WOFF) {
            *(float4*)&L0[4] = *(const float4*)(base + 4);
            *(float4*)&L1[4] = *(const float4*)(base + LST + 4);
            *(float4*)&L2[4] = *(const float4*)(base + 2 * LST + 4);
        } else {
            *(float2*)&L0[4] = *(const float2*)(base + 4);
            *(float2*)&L1[4] = *(const float2*)(base + LST + 4);
            *(float2*)&L2[4] = *(const float2*)(base + 2 * LST + 4);
        }

        float acc[4] = {0.f, 0.f, 0.f, 0.f};
#pragma unroll
        for (int k = 0; k < 8; ++k) {
            const float w0 = Wt[9*k+0], w1 = Wt[9*k+1], w2 = Wt[9*k+2];
            const float w3 = Wt[9*k+3], w4 = Wt[9*k+4], w5 = Wt[9*k+5];
            const float w6 = Wt[9*k+6], w7 = Wt[9*k+7], w8 = Wt[9*k+8];
            const float bk = bt[k];
#pragma unroll
            for (int i = 0; i < 4; ++i) {
                float d = bk;
                d = fmaf(w0, L0[WOFF+i],   d);
                d = fmaf(w1, L0[WOFF+i+1], d);
                d = fmaf(w2, L0[WOFF+i+2], d);
                d = fmaf(w3, L1[WOFF+i],   d);
                d = fmaf(w4, L1[WOFF+i+1], d);
                d = fmaf(w5, L1[WOFF+i+2], d);
                d = fmaf(w6, L2[WOFF+i],   d);
                d = fmaf(w7, L2[WOFF+i+1], d);
                d = fmaf(w8, L2[WOFF+i+2], d);
                acc[i] = gd_acc(d, acc[i]);
            }
        }

        float4 v;
        v.x = L1[WOFF+1] - acc[0] * 0.125f;
        v.y = L1[WOFF+2] - acc[1] * 0.125f;
        v.z = L1[WOFF+3] - acc[2] * 0.125f;
        v.w = L1[WOFF+4] - acc[3] * 0.125f;

        const int gy = ty0 - 3 + r;
        if (TO_GLOBAL) {
            *(float4*)&gout[gy * IMG + tx0 + c0] = v;
        } else {
            const bool ry  = (unsigned)gy < (unsigned)IMG;
            const int  gx0 = xoff + c0;
            v.x = (ry && (unsigned)(gx0 + 0) < (unsigned)IMG) ? v.x : 0.f;
            v.y = (ry && (unsigned)(gx0 + 1) < (unsigned)IMG) ? v.y : 0.f;
            v.z = (ry && (unsigned)(gx0 + 2) < (unsigned)IMG) ? v.z : 0.f;
            v.w = (ry && (unsigned)(gx0 + 3) < (unsigned)IMG) ? v.w : 0.f;
            *(float4*)&cur[r * LST + c0] = v;
        }
    }
}

__global__ __launch_bounds__(64) void deep_ad_fused(
    const float* __restrict__ x, const float* __restrict__ W,
    const float* __restrict__ b, float* __restrict__ out)
{
    __shared__ float A[SROWS * LST];
    __shared__ float Bs[SROWS * LST];

    const int tid = threadIdx.x;
    const int tx0 = blockIdx.x * TXF;
    const int ty0 = blockIdx.y * TYF;
    const float* xin  = x   + (size_t)blockIdx.z * (IMG * IMG);
    float*       gout = out + (size_t)blockIdx.z * (IMG * IMG);

    {
        float4 sv[7];
#pragma unroll
        for (int q = 0; q < 7; ++q) {
            const int item = tid + 64 * q;
            const int rr = item / 18, j = item - rr * 18;
            const int gy = ty0 - 3 + rr;
            const int gx = tx0 - 4 + 4 * j;
            float4 v = {0.f, 0.f, 0.f, 0.f};
            if (item < NSTAGE && (unsigned)gy < (unsigned)IMG && (unsigned)gx < (unsigned)IMG)
                v = *(const float4*)(xin + gy * IMG + gx);
            sv[q] = v;
        }
#pragma unroll
        for (int q = 0; q < 7; ++q) {
            const int item = tid + 64 * q;
            if (item < NSTAGE) *(float4*)&A[item * 4] = sv[q];
        }
    }
    __syncthreads();

    diffuse_step<1, TYF + 4, 1, 17, false>(A,  Bs, W + 0,   b + 0,  tx0 - 2, ty0, tx0, tid, nullptr);
    __syncthreads();
    diffuse_step<0, TYF + 2, 2, 17, false>(Bs, A,  W + 72,  b + 8,  tx0 - 1, ty0, tx0, tid, nullptr);
    __syncthreads();
    diffuse_step<0, TYF,     3, 16, true >(A, nullptr, W + 144, b + 16, 0, ty0, tx0, tid, gout);
}

extern "C" void kernel_launch(void* const* d_in, const int* in_sizes, int n_in,
                              void* d_out, int out_size, void* d_ws, size_t ws_size,
                              hipStream_t stream)
{
    const float* x = (const float*)d_in[0];
    const float* W = (const float*)d_in[1];  // [3,8,1,3,3]
    const float* b = (const float*)d_in[2];  // [3,8]
    float* out = (float*)d_out;
    const int N = in_sizes[0] / (IMG * IMG); // 16

    const size_t imgBytes = (size_t)N * IMG * IMG * sizeof(float);
    const size_t wsNeed   = 32768 + imgBytes;
    if (ws_size >= wsNeed) {
        float* wp  = (float*)d_ws;                       // 192 floats used
        float* img = (float*)((char*)d_ws + 32768);      // intermediate image
        pack_weights<<<1, 64, 0, stream>>>(W, b, wp);
        dim3 g(IMG / 64, IMG / 16, N);                   // (8, 32, 16)
        ad_step<<<g, 256, 0, stream>>>(x,   out, wp + 0);
        ad_step<<<g, 256, 0, stream>>>(out, img, wp + 64);
        ad_step<<<g, 256, 0, stream>>>(img, out, wp + 128);
    } else {
        dim3 grid(IMG / TXF, IMG / TYF, N);
        deep_ad_fused<<<grid, 64, 0, stream>>>(x, W, b, out);
    }
}